// Round 3
// baseline (1225.475 us; speedup 1.0000x reference)
//
#include <hip/hip_runtime.h>
#include <hip/hip_bf16.h>

#define N_NODES 100000
#define N_EDGES 1600000
#define F_IN 128
#define HID 64

typedef __attribute__((ext_vector_type(8))) short short8;

__device__ __forceinline__ float bfbits2f(unsigned short u) {
    union { unsigned int i; float f; } v;
    v.i = ((unsigned int)u) << 16;
    return v.f;
}
__device__ __forceinline__ unsigned short f2bfbits(float f) {
    union { float f; unsigned int i; } v;
    v.f = f;
    unsigned int r = v.i + 0x7FFFu + ((v.i >> 16) & 1u);  // RNE
    return (unsigned short)(r >> 16);
}
__device__ __forceinline__ unsigned int pack2bf(float a, float b) {
    return ((unsigned int)f2bfbits(b) << 16) | (unsigned int)f2bfbits(a);
}

// ---- runtime flags: flag[0] = edge_index is int64; flag[1] = model dtype is bf16 ----
__global__ void k_detect(const int* __restrict__ ei, const unsigned int* __restrict__ x32,
                         int* __restrict__ flag) {
    __shared__ int s_odd, s_cnt;
    if (threadIdx.x == 0) { s_odd = 0; s_cnt = 0; }
    __syncthreads();
    int t = threadIdx.x;  // blockDim.x == 1024
    if (ei[2 * t + 1] != 0) atomicOr(&s_odd, 1);
    if (t < 256) {
        unsigned int u = x32[t];
        unsigned int e = (u >> 7) & 0xFF;  // exponent field of LOW bf16 half (or fp32 mantissa bits)
        if (e >= 0x68 && e <= 0x97) atomicAdd(&s_cnt, 1);
    }
    __syncthreads();
    if (t == 0) {
        flag[0] = (s_odd == 0) ? 1 : 0;   // int64 indices
        flag[1] = (s_cnt >= 160) ? 1 : 0; // bf16 model
    }
}

__device__ __forceinline__ int clampN(int v) {
    v = v < 0 ? 0 : v;
    return v > (N_NODES - 1) ? (N_NODES - 1) : v;
}
__device__ __forceinline__ int load_row(const int* __restrict__ ei, int f, int e) {
    return clampN(f ? ei[2 * e] : ei[e]);
}
__device__ __forceinline__ int load_col(const int* __restrict__ ei, int f, int e) {
    return clampN(f ? ei[2 * (N_EDGES + e)] : ei[N_EDGES + e]);
}

// ---- fp32 weight scratch layout (floats) ----
#define WF_W1   0
#define WF_W2   8192
#define WF_L1W  12288
#define WF_B1   20480
#define WF_B2   20544
#define WF_L1B  20608
#define WF_L2W  20672
#define WF_L2B  20800
#define WF_TOT  20802

__global__ void k_prep(const void* W1, const void* W2, const void* L1W,
                       const void* b1, const void* b2, const void* L1b,
                       const void* L2W, const void* L2b,
                       const int* __restrict__ flag, float* __restrict__ Wf) {
    int idx = blockIdx.x * blockDim.x + threadIdx.x;
    if (idx >= WF_TOT) return;
    int bf = flag[1];
    const void* src; int k;
    if      (idx < WF_W2)  { src = W1;  k = idx; }
    else if (idx < WF_L1W) { src = W2;  k = idx - WF_W2; }
    else if (idx < WF_B1)  { src = L1W; k = idx - WF_L1W; }
    else if (idx < WF_B2)  { src = b1;  k = idx - WF_B1; }
    else if (idx < WF_L1B) { src = b2;  k = idx - WF_B2; }
    else if (idx < WF_L2W) { src = L1b; k = idx - WF_L1B; }
    else if (idx < WF_L2B) { src = L2W; k = idx - WF_L2W; }
    else                   { src = L2b; k = idx - WF_L2B; }
    Wf[idx] = bf ? bfbits2f(((const unsigned short*)src)[k]) : ((const float*)src)[k];
}

__global__ void k_deg(const int* __restrict__ ei, const int* __restrict__ flag,
                      int* __restrict__ deg) {
    int e = blockIdx.x * blockDim.x + threadIdx.x;
    if (e >= N_EDGES) return;
    atomicAdd(&deg[load_col(ei, flag[0], e)], 1);
}

__global__ void k_dinv(const int* __restrict__ deg, float* __restrict__ dinv) {
    int i = blockIdx.x * blockDim.x + threadIdx.x;
    if (i < N_NODES) dinv[i] = rsqrtf((float)(deg[i] + 1));
}

// ---- hs storage: compact -> packed bf16 pairs [N][32]u32, else fp32 [N][64] ----
__device__ __forceinline__ float ld_hs(const void* hs, int node, int j, int compact) {
    if (compact) {
        unsigned int w = ((const unsigned int*)hs)[(size_t)node * 32 + (j >> 1)];
        return bfbits2f((unsigned short)((j & 1) ? (w >> 16) : (w & 0xFFFF)));
    }
    return ((const float*)hs)[(size_t)node * 64 + j];
}
__device__ __forceinline__ void st_hs(void* hs, int node, const float* acc, float s, int compact) {
    if (compact) {
        unsigned int* op = (unsigned int*)hs + (size_t)node * 32;
#pragma unroll
        for (int j = 0; j < 64; j += 2) op[j >> 1] = pack2bf(acc[j] * s, acc[j + 1] * s);
    } else {
        float* op = (float*)hs + (size_t)node * 64;
#pragma unroll
        for (int j = 0; j < 64; j += 4)
            *(float4*)(op + j) = make_float4(acc[j] * s, acc[j+1] * s, acc[j+2] * s, acc[j+3] * s);
    }
}

__device__ __forceinline__ void fma8(const float* xv, const float* __restrict__ Wf,
                                     int k0, float* acc) {
#pragma unroll
    for (int t = 0; t < 8; t++) {
        const float* wr = Wf + (k0 + t) * 64;
#pragma unroll
        for (int j = 0; j < 64; j++) acc[j] = fmaf(xv[t], wr[j], acc[j]);
    }
}

// ---- layer-1 GEMM: x [N,128] (bf16 or fp32) @ Wf[128,64]; out = dinv[i]*(x@W) ----
__global__ void __launch_bounds__(256) k_gemm_in(const void* __restrict__ x,
                                                 const float* __restrict__ Wf,
                                                 const float* __restrict__ dinv,
                                                 void* __restrict__ out,
                                                 const int* __restrict__ flag, int compact) {
    int i = blockIdx.x * blockDim.x + threadIdx.x;
    if (i >= N_NODES) return;
    int bf = flag[1];
    float acc[64];
#pragma unroll
    for (int j = 0; j < 64; j++) acc[j] = 0.f;
    if (bf) {
        const unsigned short* xp = (const unsigned short*)x + (size_t)i * F_IN;
#pragma unroll 2
        for (int k0 = 0; k0 < F_IN; k0 += 8) {
            short8 raw = *(const short8*)(xp + k0);
            float xv[8];
#pragma unroll
            for (int t = 0; t < 8; t++) xv[t] = bfbits2f((unsigned short)raw[t]);
            fma8(xv, Wf, k0, acc);
        }
    } else {
        const float* xp = (const float*)x + (size_t)i * F_IN;
#pragma unroll 2
        for (int k0 = 0; k0 < F_IN; k0 += 8) {
            float4 a = *(const float4*)(xp + k0);
            float4 b = *(const float4*)(xp + k0 + 4);
            float xv[8] = {a.x, a.y, a.z, a.w, b.x, b.y, b.z, b.w};
            fma8(xv, Wf, k0, acc);
        }
    }
    st_hs(out, i, acc, dinv[i], compact);
}

// ---- layer-2 GEMM: h fp32 [N,64] @ Wf[64,64]; out = dinv[i]*(h@W) ----
__global__ void __launch_bounds__(256) k_gemm_h(const float* __restrict__ h,
                                                const float* __restrict__ Wf,
                                                const float* __restrict__ dinv,
                                                void* __restrict__ out, int compact) {
    int i = blockIdx.x * blockDim.x + threadIdx.x;
    if (i >= N_NODES) return;
    float acc[64];
#pragma unroll
    for (int j = 0; j < 64; j++) acc[j] = 0.f;
    const float* hp = h + (size_t)i * 64;
#pragma unroll 2
    for (int k0 = 0; k0 < 64; k0 += 8) {
        float4 a = *(const float4*)(hp + k0);
        float4 b = *(const float4*)(hp + k0 + 4);
        float xv[8] = {a.x, a.y, a.z, a.w, b.x, b.y, b.z, b.w};
        fma8(xv, Wf, k0, acc);
    }
    st_hs(out, i, acc, dinv[i], compact);
}

// ---- scatter: acc[col[e]][j] += hs[row[e]][j] ----
__global__ void k_scatter(const int* __restrict__ ei, const int* __restrict__ flag,
                          const void* __restrict__ hs, float* __restrict__ acc, int compact) {
    long long idx = (long long)blockIdx.x * blockDim.x + threadIdx.x;
    if (idx >= (long long)N_EDGES * HID) return;
    int e = (int)(idx >> 6), j = (int)(idx & 63);
    int f = flag[0];
    int r = load_row(ei, f, e), c = load_col(ei, f, e);
    atomicAdd(acc + (size_t)c * 64 + j, ld_hs(hs, r, j, compact));
}

// ---- finalize: acc = relu((acc + hs[i])*dinv[i] + b[j]) in place ----
__global__ void k_finalize(float* __restrict__ acc, const void* __restrict__ hs,
                           const float* __restrict__ dinv, const float* __restrict__ bias,
                           int compact) {
    int idx = blockIdx.x * blockDim.x + threadIdx.x;
    if (idx >= N_NODES * HID) return;
    int i = idx >> 6, j = idx & 63;
    float v = (acc[idx] + ld_hs(hs, i, j, compact)) * dinv[i] + bias[j];
    acc[idx] = fmaxf(v, 0.f);
}

// ---- per-node projections P1 = h@L1W[:64], P2 = h@L1W[64:] ----
// compact:        P1 packed bf16 [N][32]u32 in PA; P2 packed bf16 into h's row (in place)
// full & bf16:    P1|P2 packed bf16 [N][64]u32 in PA
// full & fp32:    P1 fp32 [N][64] in PA; P2 fp32 overwrites h row (in place)
__global__ void __launch_bounds__(256) k_gemm_pair(float* __restrict__ h,
                                                   const float* __restrict__ Wf,  // [128][64]
                                                   void* __restrict__ PA,
                                                   const int* __restrict__ flag, int compact) {
    int i = blockIdx.x * blockDim.x + threadIdx.x;
    if (i >= N_NODES) return;
    int bf = flag[1];
    float a0[64], a1[64];
#pragma unroll
    for (int j = 0; j < 64; j++) { a0[j] = 0.f; a1[j] = 0.f; }
    const float* hp = h + (size_t)i * 64;
#pragma unroll 1
    for (int k0 = 0; k0 < 64; k0 += 8) {
        float4 a = *(const float4*)(hp + k0);
        float4 b = *(const float4*)(hp + k0 + 4);
        float xv[8] = {a.x, a.y, a.z, a.w, b.x, b.y, b.z, b.w};
#pragma unroll
        for (int t = 0; t < 8; t++) {
            const float* wrA = Wf + (k0 + t) * 64;
            const float* wrB = Wf + (64 + k0 + t) * 64;
#pragma unroll
            for (int j = 0; j < 64; j++) {
                a0[j] = fmaf(xv[t], wrA[j], a0[j]);
                a1[j] = fmaf(xv[t], wrB[j], a1[j]);
            }
        }
    }
    if (compact) {
        unsigned int* p1 = (unsigned int*)PA + (size_t)i * 32;
        unsigned int* p2 = (unsigned int*)(h + (size_t)i * 64);  // own row, fully read already
#pragma unroll
        for (int j = 0; j < 64; j += 2) {
            p1[j >> 1] = pack2bf(a0[j], a0[j + 1]);
            p2[j >> 1] = pack2bf(a1[j], a1[j + 1]);
        }
    } else if (bf) {
        unsigned int* op = (unsigned int*)PA + (size_t)i * 64;
#pragma unroll
        for (int j = 0; j < 64; j += 2) {
            op[j >> 1]        = pack2bf(a0[j], a0[j + 1]);
            op[32 + (j >> 1)] = pack2bf(a1[j], a1[j + 1]);
        }
    } else {
        float* p1 = (float*)PA + (size_t)i * 64;
        float* p2 = h + (size_t)i * 64;
#pragma unroll
        for (int j = 0; j < 64; j += 4) {
            *(float4*)(p1 + j) = make_float4(a0[j], a0[j+1], a0[j+2], a0[j+3]);
            *(float4*)(p2 + j) = make_float4(a1[j], a1[j+1], a1[j+2], a1[j+3]);
        }
    }
}

__device__ __forceinline__ void edge_acc_bf(const unsigned int* p1, const unsigned int* p2,
                                            const float* l1b, const float* l2w,
                                            float& s0, float& s1) {
#pragma unroll
    for (int q = 0; q < 8; q++) {
        uint4 ua = ((const uint4*)p1)[q];
        uint4 ub = ((const uint4*)p2)[q];
        unsigned int wa[4] = {ua.x, ua.y, ua.z, ua.w};
        unsigned int wb[4] = {ub.x, ub.y, ub.z, ub.w};
#pragma unroll
        for (int t = 0; t < 4; t++) {
            int j = q * 8 + t * 2;
            float a0 = bfbits2f((unsigned short)(wa[t] & 0xFFFF));
            float a1 = bfbits2f((unsigned short)(wa[t] >> 16));
            float b0 = bfbits2f((unsigned short)(wb[t] & 0xFFFF));
            float b1 = bfbits2f((unsigned short)(wb[t] >> 16));
            float z;
            z = fmaxf(a0 + b0 + l1b[j + 0], 0.f);
            s0 = fmaf(z, l2w[(j + 0) * 2], s0); s1 = fmaf(z, l2w[(j + 0) * 2 + 1], s1);
            z = fmaxf(a1 + b1 + l1b[j + 1], 0.f);
            s0 = fmaf(z, l2w[(j + 1) * 2], s0); s1 = fmaf(z, l2w[(j + 1) * 2 + 1], s1);
        }
    }
}

// ---- edge MLP + log_softmax ----
__global__ void k_edge(const int* __restrict__ ei, const int* __restrict__ flag,
                       const void* __restrict__ PA, const float* __restrict__ h,
                       const float* __restrict__ Wf, void* __restrict__ out, int compact) {
    int e = blockIdx.x * blockDim.x + threadIdx.x;
    if (e >= N_EDGES) return;
    int f = flag[0], bf = flag[1];
    int r = load_row(ei, f, e), c = load_col(ei, f, e);
    const float* l1b = Wf + WF_L1B;
    const float* l2w = Wf + WF_L2W;
    const float* l2b = Wf + WF_L2B;
    float s0 = 0.f, s1 = 0.f;
    if (!bf && !compact) {
        const float4* Pr = (const float4*)((const float*)PA + (size_t)r * 64);
        const float4* Pc = (const float4*)(h + (size_t)c * 64);
#pragma unroll
        for (int q = 0; q < 16; q++) {
            float4 a = Pr[q];
            float4 b = Pc[q];
            int j = q * 4;
            float z;
            z = fmaxf(a.x + b.x + l1b[j + 0], 0.f);
            s0 = fmaf(z, l2w[(j + 0) * 2], s0); s1 = fmaf(z, l2w[(j + 0) * 2 + 1], s1);
            z = fmaxf(a.y + b.y + l1b[j + 1], 0.f);
            s0 = fmaf(z, l2w[(j + 1) * 2], s0); s1 = fmaf(z, l2w[(j + 1) * 2 + 1], s1);
            z = fmaxf(a.z + b.z + l1b[j + 2], 0.f);
            s0 = fmaf(z, l2w[(j + 2) * 2], s0); s1 = fmaf(z, l2w[(j + 2) * 2 + 1], s1);
            z = fmaxf(a.w + b.w + l1b[j + 3], 0.f);
            s0 = fmaf(z, l2w[(j + 3) * 2], s0); s1 = fmaf(z, l2w[(j + 3) * 2 + 1], s1);
        }
    } else {
        const unsigned int* p1;
        const unsigned int* p2;
        if (compact) {
            p1 = (const unsigned int*)PA + (size_t)r * 32;
            p2 = (const unsigned int*)(h + (size_t)c * 64);
        } else {
            p1 = (const unsigned int*)PA + (size_t)r * 64;
            p2 = (const unsigned int*)PA + (size_t)c * 64 + 32;
        }
        edge_acc_bf(p1, p2, l1b, l2w, s0, s1);
    }
    float z0 = s0 + l2b[0];
    float z1 = s1 + l2b[1];
    float m = fmaxf(z0, z1);
    float lse = m + __logf(__expf(z0 - m) + __expf(z1 - m));
    if (bf) {
        ((unsigned int*)out)[e] = pack2bf(z0 - lse, z1 - lse);
    } else {
        float2 v; v.x = z0 - lse; v.y = z1 - lse;
        ((float2*)out)[e] = v;
    }
}

extern "C" void kernel_launch(void* const* d_in, const int* in_sizes, int n_in,
                              void* d_out, int out_size, void* d_ws, size_t ws_size,
                              hipStream_t stream) {
    const void* x   = d_in[0];
    const int*  ei  = (const int*)d_in[1];

    char* ws = (char*)d_ws;
    constexpr size_t MB = 1024 * 1024;
    const int compact = (ws_size < 56 * MB) ? 1 : 0;

    int*   deg  = (int*)(ws);                  // 400 KB
    float* dinv = (float*)(ws + 512 * 1024);   // 400 KB
    int*   flag = (int*)(ws + 960 * 1024);     // 8 B
    float* Wf   = (float*)(ws + 1 * MB);       // 83 KB
    void*  bufA = (void*)(ws + 2 * MB);        // hs / P1: 25.6 MB (full) or 12.8 MB (compact)
    float* bufB = (float*)(ws + 2 * MB + (compact ? 13 : 26) * MB);  // acc/h: 25.6 MB

    hipMemsetAsync(deg, 0, N_NODES * sizeof(int), stream);
    hipMemsetAsync(bufB, 0, (size_t)N_NODES * 64 * 4, stream);

    k_detect<<<1, 1024, 0, stream>>>(ei, (const unsigned int*)x, flag);
    k_prep<<<(WF_TOT + 255) / 256, 256, 0, stream>>>(d_in[2], d_in[4], d_in[6], d_in[3],
                                                     d_in[5], d_in[7], d_in[8], d_in[9],
                                                     flag, Wf);
    k_deg<<<(N_EDGES + 255) / 256, 256, 0, stream>>>(ei, flag, deg);
    k_dinv<<<(N_NODES + 255) / 256, 256, 0, stream>>>(deg, dinv);

    // layer 1
    k_gemm_in<<<(N_NODES + 255) / 256, 256, 0, stream>>>(x, Wf + WF_W1, dinv, bufA, flag, compact);
    k_scatter<<<(N_EDGES * HID + 255) / 256, 256, 0, stream>>>(ei, flag, bufA, bufB, compact);
    k_finalize<<<(N_NODES * HID + 255) / 256, 256, 0, stream>>>(bufB, bufA, dinv, Wf + WF_B1, compact);

    // layer 2
    k_gemm_h<<<(N_NODES + 255) / 256, 256, 0, stream>>>(bufB, Wf + WF_W2, dinv, bufA, compact);
    hipMemsetAsync(bufB, 0, (size_t)N_NODES * 64 * 4, stream);
    k_scatter<<<(N_EDGES * HID + 255) / 256, 256, 0, stream>>>(ei, flag, bufA, bufB, compact);
    k_finalize<<<(N_NODES * HID + 255) / 256, 256, 0, stream>>>(bufB, bufA, dinv, Wf + WF_B2, compact);

    // edge MLP via per-node projections
    k_gemm_pair<<<(N_NODES + 255) / 256, 256, 0, stream>>>(bufB, Wf + WF_L1W, bufA, flag, compact);
    k_edge<<<(N_EDGES + 255) / 256, 256, 0, stream>>>(ei, flag, bufA, bufB, Wf, d_out, compact);
}

// Round 4
// 828.887 us; speedup vs baseline: 1.4785x; 1.4785x over previous
//
#include <hip/hip_runtime.h>
#include <hip/hip_bf16.h>

#define N_NODES 100000
#define N_EDGES 1600000
#define F_IN 128
#define HID 64
#define SCAN_NB 98  // ceil(100000/1024)

typedef __attribute__((ext_vector_type(8))) short short8;

__device__ __forceinline__ float bfbits2f(unsigned short u) {
    union { unsigned int i; float f; } v;
    v.i = ((unsigned int)u) << 16;
    return v.f;
}
__device__ __forceinline__ unsigned short f2bfbits(float f) {
    union { float f; unsigned int i; } v;
    v.f = f;
    unsigned int r = v.i + 0x7FFFu + ((v.i >> 16) & 1u);  // RNE
    return (unsigned short)(r >> 16);
}
__device__ __forceinline__ unsigned int pack2bf(float a, float b) {
    return ((unsigned int)f2bfbits(b) << 16) | (unsigned int)f2bfbits(a);
}

// ---- runtime flags: flag[0] = edge_index is int64; flag[1] = model dtype is bf16 ----
__global__ void k_detect(const int* __restrict__ ei, const unsigned int* __restrict__ x32,
                         int* __restrict__ flag) {
    __shared__ int s_odd, s_cnt;
    if (threadIdx.x == 0) { s_odd = 0; s_cnt = 0; }
    __syncthreads();
    int t = threadIdx.x;  // blockDim.x == 1024
    if (ei[2 * t + 1] != 0) atomicOr(&s_odd, 1);
    if (t < 256) {
        unsigned int u = x32[t];
        unsigned int e = (u >> 7) & 0xFF;
        if (e >= 0x68 && e <= 0x97) atomicAdd(&s_cnt, 1);
    }
    __syncthreads();
    if (t == 0) {
        flag[0] = (s_odd == 0) ? 1 : 0;
        flag[1] = (s_cnt >= 160) ? 1 : 0;
    }
}

__device__ __forceinline__ int clampN(int v) {
    v = v < 0 ? 0 : v;
    return v > (N_NODES - 1) ? (N_NODES - 1) : v;
}
__device__ __forceinline__ int load_row(const int* __restrict__ ei, int f, int e) {
    return clampN(f ? ei[2 * e] : ei[e]);
}
__device__ __forceinline__ int load_col(const int* __restrict__ ei, int f, int e) {
    return clampN(f ? ei[2 * (N_EDGES + e)] : ei[N_EDGES + e]);
}

// ---- fp32 weight scratch layout (floats) ----
#define WF_W1   0
#define WF_W2   8192
#define WF_L1W  12288
#define WF_B1   20480
#define WF_B2   20544
#define WF_L1B  20608
#define WF_L2W  20672
#define WF_L2B  20800
#define WF_TOT  20802

__global__ void k_prep(const void* W1, const void* W2, const void* L1W,
                       const void* b1, const void* b2, const void* L1b,
                       const void* L2W, const void* L2b,
                       const int* __restrict__ flag, float* __restrict__ Wf) {
    int idx = blockIdx.x * blockDim.x + threadIdx.x;
    if (idx >= WF_TOT) return;
    int bf = flag[1];
    const void* src; int k;
    if      (idx < WF_W2)  { src = W1;  k = idx; }
    else if (idx < WF_L1W) { src = W2;  k = idx - WF_W2; }
    else if (idx < WF_B1)  { src = L1W; k = idx - WF_L1W; }
    else if (idx < WF_B2)  { src = b1;  k = idx - WF_B1; }
    else if (idx < WF_L1B) { src = b2;  k = idx - WF_B2; }
    else if (idx < WF_L2W) { src = L1b; k = idx - WF_L1B; }
    else if (idx < WF_L2B) { src = L2W; k = idx - WF_L2W; }
    else                   { src = L2b; k = idx - WF_L2B; }
    Wf[idx] = bf ? bfbits2f(((const unsigned short*)src)[k]) : ((const float*)src)[k];
}

__global__ void k_deg(const int* __restrict__ ei, const int* __restrict__ flag,
                      int* __restrict__ deg) {
    int e = blockIdx.x * blockDim.x + threadIdx.x;
    if (e >= N_EDGES) return;
    atomicAdd(&deg[load_col(ei, flag[0], e)], 1);
}

__global__ void k_dinv(const int* __restrict__ deg, float* __restrict__ dinv) {
    int i = blockIdx.x * blockDim.x + threadIdx.x;
    if (i < N_NODES) dinv[i] = rsqrtf((float)(deg[i] + 1));
}

// ---- CSR build: exclusive scan of deg -> rowptr, then fill ----
__global__ void k_scan1(const int* __restrict__ deg, int* __restrict__ rowptr,
                        int* __restrict__ bsum) {
    __shared__ int s[1024];
    int t = threadIdx.x, b = blockIdx.x;
    int i = b * 1024 + t;
    int v = (i < N_NODES) ? deg[i] : 0;
    s[t] = v; __syncthreads();
    for (int off = 1; off < 1024; off <<= 1) {
        int add = (t >= off) ? s[t - off] : 0;
        __syncthreads();
        s[t] += add;
        __syncthreads();
    }
    if (i < N_NODES) rowptr[i] = s[t] - v;
    if (t == 1023) bsum[b] = s[t];
}

__global__ void k_scan2(const int* __restrict__ bsum, int* __restrict__ boff,
                        int* __restrict__ rowptr) {
    __shared__ int s[128];
    int t = threadIdx.x;
    int v = (t < SCAN_NB) ? bsum[t] : 0;
    s[t] = v; __syncthreads();
    for (int off = 1; off < 128; off <<= 1) {
        int add = (t >= off) ? s[t - off] : 0;
        __syncthreads();
        s[t] += add;
        __syncthreads();
    }
    if (t < SCAN_NB) boff[t] = s[t] - v;
    if (t == 0) rowptr[N_NODES] = N_EDGES;
}

__global__ void k_scan3(int* __restrict__ rowptr, const int* __restrict__ boff) {
    int t = threadIdx.x, b = blockIdx.x;
    int i = b * 1024 + t;
    if (i < N_NODES) rowptr[i] += boff[b];
}

__global__ void k_fill(const int* __restrict__ ei, const int* __restrict__ flag,
                       const int* __restrict__ rowptr, int* __restrict__ cursor,
                       int* __restrict__ csr_src) {
    int e = blockIdx.x * blockDim.x + threadIdx.x;
    if (e >= N_EDGES) return;
    int f = flag[0];
    int r = load_row(ei, f, e), c = load_col(ei, f, e);
    int pos = atomicAdd(&cursor[c], 1);
    csr_src[rowptr[c] + pos] = r;
}

// ---- hs storage: compact -> packed bf16 pairs [N][32]u32, else fp32 [N][64] ----
__device__ __forceinline__ float ld_hs(const void* hs, int node, int j, int compact) {
    if (compact) {
        unsigned int w = ((const unsigned int*)hs)[(size_t)node * 32 + (j >> 1)];
        return bfbits2f((unsigned short)((j & 1) ? (w >> 16) : (w & 0xFFFF)));
    }
    return ((const float*)hs)[(size_t)node * 64 + j];
}
__device__ __forceinline__ void st_hs(void* hs, int node, const float* acc, float s, int compact) {
    if (compact) {
        unsigned int* op = (unsigned int*)hs + (size_t)node * 32;
#pragma unroll
        for (int j = 0; j < 64; j += 2) op[j >> 1] = pack2bf(acc[j] * s, acc[j + 1] * s);
    } else {
        float* op = (float*)hs + (size_t)node * 64;
#pragma unroll
        for (int j = 0; j < 64; j += 4)
            *(float4*)(op + j) = make_float4(acc[j] * s, acc[j+1] * s, acc[j+2] * s, acc[j+3] * s);
    }
}

__device__ __forceinline__ void fma8(const float* xv, const float* __restrict__ Wf,
                                     int k0, float* acc) {
#pragma unroll
    for (int t = 0; t < 8; t++) {
        const float* wr = Wf + (k0 + t) * 64;
#pragma unroll
        for (int j = 0; j < 64; j++) acc[j] = fmaf(xv[t], wr[j], acc[j]);
    }
}

// ---- layer-1 GEMM: x [N,128] (bf16 or fp32) @ Wf[128,64]; out = dinv[i]*(x@W) ----
__global__ void __launch_bounds__(256) k_gemm_in(const void* __restrict__ x,
                                                 const float* __restrict__ Wf,
                                                 const float* __restrict__ dinv,
                                                 void* __restrict__ out,
                                                 const int* __restrict__ flag, int compact) {
    int i = blockIdx.x * blockDim.x + threadIdx.x;
    if (i >= N_NODES) return;
    int bf = flag[1];
    float acc[64];
#pragma unroll
    for (int j = 0; j < 64; j++) acc[j] = 0.f;
    if (bf) {
        const unsigned short* xp = (const unsigned short*)x + (size_t)i * F_IN;
#pragma unroll 2
        for (int k0 = 0; k0 < F_IN; k0 += 8) {
            short8 raw = *(const short8*)(xp + k0);
            float xv[8];
#pragma unroll
            for (int t = 0; t < 8; t++) xv[t] = bfbits2f((unsigned short)raw[t]);
            fma8(xv, Wf, k0, acc);
        }
    } else {
        const float* xp = (const float*)x + (size_t)i * F_IN;
#pragma unroll 2
        for (int k0 = 0; k0 < F_IN; k0 += 8) {
            float4 a = *(const float4*)(xp + k0);
            float4 b = *(const float4*)(xp + k0 + 4);
            float xv[8] = {a.x, a.y, a.z, a.w, b.x, b.y, b.z, b.w};
            fma8(xv, Wf, k0, acc);
        }
    }
    st_hs(out, i, acc, dinv[i], compact);
}

// ---- layer-2 GEMM: h fp32 [N,64] @ Wf[64,64]; out = dinv[i]*(h@W) ----
__global__ void __launch_bounds__(256) k_gemm_h(const float* __restrict__ h,
                                                const float* __restrict__ Wf,
                                                const float* __restrict__ dinv,
                                                void* __restrict__ out, int compact) {
    int i = blockIdx.x * blockDim.x + threadIdx.x;
    if (i >= N_NODES) return;
    float acc[64];
#pragma unroll
    for (int j = 0; j < 64; j++) acc[j] = 0.f;
    const float* hp = h + (size_t)i * 64;
#pragma unroll 2
    for (int k0 = 0; k0 < 64; k0 += 8) {
        float4 a = *(const float4*)(hp + k0);
        float4 b = *(const float4*)(hp + k0 + 4);
        float xv[8] = {a.x, a.y, a.z, a.w, b.x, b.y, b.z, b.w};
        fma8(xv, Wf, k0, acc);
    }
    st_hs(out, i, acc, dinv[i], compact);
}

// ---- fused aggregate: one wave per node; lane = channel ----
// h[i] = relu( dinv[i] * (hs[i] + sum_{r in in(i)} hs[r]) + bias )
__global__ void __launch_bounds__(256) k_agg(const void* __restrict__ hs,
                                             const int* __restrict__ rowptr,
                                             const int* __restrict__ csr_src,
                                             const float* __restrict__ dinv,
                                             const float* __restrict__ bias,
                                             float* __restrict__ h, int compact) {
    int wid = blockIdx.x * (blockDim.x >> 6) + (threadIdx.x >> 6);
    int lane = threadIdx.x & 63;
    if (wid >= N_NODES) return;
    float acc = ld_hs(hs, wid, lane, compact);  // self-loop
    int k = rowptr[wid], k1 = rowptr[wid + 1];
    for (; k + 1 < k1; k += 2) {
        int s0 = csr_src[k], s1 = csr_src[k + 1];
        float v0 = ld_hs(hs, s0, lane, compact);
        float v1 = ld_hs(hs, s1, lane, compact);
        acc += v0 + v1;
    }
    if (k < k1) acc += ld_hs(hs, csr_src[k], lane, compact);
    h[(size_t)wid * 64 + lane] = fmaxf(acc * dinv[wid] + bias[lane], 0.f);
}

// ---- per-node projections P1 = h@L1W[:64], P2 = h@L1W[64:] ----
__global__ void __launch_bounds__(256) k_gemm_pair(float* __restrict__ h,
                                                   const float* __restrict__ Wf,  // [128][64]
                                                   void* __restrict__ PA,
                                                   const int* __restrict__ flag, int compact) {
    int i = blockIdx.x * blockDim.x + threadIdx.x;
    if (i >= N_NODES) return;
    int bf = flag[1];
    float a0[64], a1[64];
#pragma unroll
    for (int j = 0; j < 64; j++) { a0[j] = 0.f; a1[j] = 0.f; }
    const float* hp = h + (size_t)i * 64;
#pragma unroll 1
    for (int k0 = 0; k0 < 64; k0 += 8) {
        float4 a = *(const float4*)(hp + k0);
        float4 b = *(const float4*)(hp + k0 + 4);
        float xv[8] = {a.x, a.y, a.z, a.w, b.x, b.y, b.z, b.w};
#pragma unroll
        for (int t = 0; t < 8; t++) {
            const float* wrA = Wf + (k0 + t) * 64;
            const float* wrB = Wf + (64 + k0 + t) * 64;
#pragma unroll
            for (int j = 0; j < 64; j++) {
                a0[j] = fmaf(xv[t], wrA[j], a0[j]);
                a1[j] = fmaf(xv[t], wrB[j], a1[j]);
            }
        }
    }
    if (compact) {
        unsigned int* p1 = (unsigned int*)PA + (size_t)i * 32;
        unsigned int* p2 = (unsigned int*)(h + (size_t)i * 64);
#pragma unroll
        for (int j = 0; j < 64; j += 2) {
            p1[j >> 1] = pack2bf(a0[j], a0[j + 1]);
            p2[j >> 1] = pack2bf(a1[j], a1[j + 1]);
        }
    } else if (bf) {
        unsigned int* op = (unsigned int*)PA + (size_t)i * 64;
#pragma unroll
        for (int j = 0; j < 64; j += 2) {
            op[j >> 1]        = pack2bf(a0[j], a0[j + 1]);
            op[32 + (j >> 1)] = pack2bf(a1[j], a1[j + 1]);
        }
    } else {
        float* p1 = (float*)PA + (size_t)i * 64;
        float* p2 = h + (size_t)i * 64;
#pragma unroll
        for (int j = 0; j < 64; j += 4) {
            *(float4*)(p1 + j) = make_float4(a0[j], a0[j+1], a0[j+2], a0[j+3]);
            *(float4*)(p2 + j) = make_float4(a1[j], a1[j+1], a1[j+2], a1[j+3]);
        }
    }
}

__device__ __forceinline__ void edge_acc_bf(const unsigned int* p1, const unsigned int* p2,
                                            const float* l1b, const float* l2w,
                                            float& s0, float& s1) {
#pragma unroll
    for (int q = 0; q < 8; q++) {
        uint4 ua = ((const uint4*)p1)[q];
        uint4 ub = ((const uint4*)p2)[q];
        unsigned int wa[4] = {ua.x, ua.y, ua.z, ua.w};
        unsigned int wb[4] = {ub.x, ub.y, ub.z, ub.w};
#pragma unroll
        for (int t = 0; t < 4; t++) {
            int j = q * 8 + t * 2;
            float a0 = bfbits2f((unsigned short)(wa[t] & 0xFFFF));
            float a1 = bfbits2f((unsigned short)(wa[t] >> 16));
            float b0 = bfbits2f((unsigned short)(wb[t] & 0xFFFF));
            float b1 = bfbits2f((unsigned short)(wb[t] >> 16));
            float z;
            z = fmaxf(a0 + b0 + l1b[j + 0], 0.f);
            s0 = fmaf(z, l2w[(j + 0) * 2], s0); s1 = fmaf(z, l2w[(j + 0) * 2 + 1], s1);
            z = fmaxf(a1 + b1 + l1b[j + 1], 0.f);
            s0 = fmaf(z, l2w[(j + 1) * 2], s0); s1 = fmaf(z, l2w[(j + 1) * 2 + 1], s1);
        }
    }
}

// ---- edge MLP + log_softmax ----
__global__ void k_edge(const int* __restrict__ ei, const int* __restrict__ flag,
                       const void* __restrict__ PA, const float* __restrict__ h,
                       const float* __restrict__ Wf, void* __restrict__ out, int compact) {
    int e = blockIdx.x * blockDim.x + threadIdx.x;
    if (e >= N_EDGES) return;
    int f = flag[0], bf = flag[1];
    int r = load_row(ei, f, e), c = load_col(ei, f, e);
    const float* l1b = Wf + WF_L1B;
    const float* l2w = Wf + WF_L2W;
    const float* l2b = Wf + WF_L2B;
    float s0 = 0.f, s1 = 0.f;
    if (!bf && !compact) {
        const float4* Pr = (const float4*)((const float*)PA + (size_t)r * 64);
        const float4* Pc = (const float4*)(h + (size_t)c * 64);
#pragma unroll
        for (int q = 0; q < 16; q++) {
            float4 a = Pr[q];
            float4 b = Pc[q];
            int j = q * 4;
            float z;
            z = fmaxf(a.x + b.x + l1b[j + 0], 0.f);
            s0 = fmaf(z, l2w[(j + 0) * 2], s0); s1 = fmaf(z, l2w[(j + 0) * 2 + 1], s1);
            z = fmaxf(a.y + b.y + l1b[j + 1], 0.f);
            s0 = fmaf(z, l2w[(j + 1) * 2], s0); s1 = fmaf(z, l2w[(j + 1) * 2 + 1], s1);
            z = fmaxf(a.z + b.z + l1b[j + 2], 0.f);
            s0 = fmaf(z, l2w[(j + 2) * 2], s0); s1 = fmaf(z, l2w[(j + 2) * 2 + 1], s1);
            z = fmaxf(a.w + b.w + l1b[j + 3], 0.f);
            s0 = fmaf(z, l2w[(j + 3) * 2], s0); s1 = fmaf(z, l2w[(j + 3) * 2 + 1], s1);
        }
    } else {
        const unsigned int* p1;
        const unsigned int* p2;
        if (compact) {
            p1 = (const unsigned int*)PA + (size_t)r * 32;
            p2 = (const unsigned int*)(h + (size_t)c * 64);
        } else {
            p1 = (const unsigned int*)PA + (size_t)r * 64;
            p2 = (const unsigned int*)PA + (size_t)c * 64 + 32;
        }
        edge_acc_bf(p1, p2, l1b, l2w, s0, s1);
    }
    float z0 = s0 + l2b[0];
    float z1 = s1 + l2b[1];
    float m = fmaxf(z0, z1);
    float lse = m + __logf(__expf(z0 - m) + __expf(z1 - m));
    if (bf) {
        ((unsigned int*)out)[e] = pack2bf(z0 - lse, z1 - lse);
    } else {
        float2 v; v.x = z0 - lse; v.y = z1 - lse;
        ((float2*)out)[e] = v;
    }
}

extern "C" void kernel_launch(void* const* d_in, const int* in_sizes, int n_in,
                              void* d_out, int out_size, void* d_ws, size_t ws_size,
                              hipStream_t stream) {
    const void* x   = d_in[0];
    const int*  ei  = (const int*)d_in[1];

    char* ws = (char*)d_ws;
    constexpr size_t MB = 1024 * 1024;
    constexpr size_t KB = 1024;
    const int compact = (ws_size < 62 * MB) ? 1 : 0;

    int*   deg    = (int*)(ws);                       // 400 KB (reused as cursor)
    float* dinv   = (float*)(ws + 512 * KB);          // 400 KB
    int*   flag   = (int*)(ws + 960 * KB);            // 8 B
    float* Wf     = (float*)(ws + 1 * MB);            // 83.2 KB
    int*   bsum   = (int*)(ws + 1 * MB + 88 * KB);    // 392 B
    int*   boff   = (int*)(ws + 1 * MB + 89 * KB);    // 392 B
    int*   rowptr = (int*)(ws + 1 * MB + 512 * KB);   // 400 KB + 4
    int*   csrsrc = (int*)(ws + 2 * MB);              // 6.4 MB
    void*  bufA   = (void*)(ws + 9 * MB);             // hs/P1: 25.6 (full) / 12.8 MB (compact)
    float* bufB   = (float*)(ws + 9 * MB + (compact ? 13 : 26) * MB);  // h: 25.6 MB

    hipMemsetAsync(deg, 0, N_NODES * sizeof(int), stream);

    k_detect<<<1, 1024, 0, stream>>>(ei, (const unsigned int*)x, flag);
    k_prep<<<(WF_TOT + 255) / 256, 256, 0, stream>>>(d_in[2], d_in[4], d_in[6], d_in[3],
                                                     d_in[5], d_in[7], d_in[8], d_in[9],
                                                     flag, Wf);
    k_deg<<<(N_EDGES + 255) / 256, 256, 0, stream>>>(ei, flag, deg);
    k_dinv<<<(N_NODES + 255) / 256, 256, 0, stream>>>(deg, dinv);

    // CSR build
    k_scan1<<<SCAN_NB, 1024, 0, stream>>>(deg, rowptr, bsum);
    k_scan2<<<1, 128, 0, stream>>>(bsum, boff, rowptr);
    k_scan3<<<SCAN_NB, 1024, 0, stream>>>(rowptr, boff);
    hipMemsetAsync(deg, 0, N_NODES * sizeof(int), stream);  // deg -> cursor
    k_fill<<<(N_EDGES + 255) / 256, 256, 0, stream>>>(ei, flag, rowptr, deg, csrsrc);

    // layer 1: hs1 -> bufA; agg -> bufB (h1)
    k_gemm_in<<<(N_NODES + 255) / 256, 256, 0, stream>>>(x, Wf + WF_W1, dinv, bufA, flag, compact);
    k_agg<<<(N_NODES * 64 + 255) / 256, 256, 0, stream>>>(bufA, rowptr, csrsrc, dinv,
                                                          Wf + WF_B1, bufB, compact);

    // layer 2: hs2 -> bufA; agg -> bufB (h2, in place over h1)
    k_gemm_h<<<(N_NODES + 255) / 256, 256, 0, stream>>>(bufB, Wf + WF_W2, dinv, bufA, compact);
    k_agg<<<(N_NODES * 64 + 255) / 256, 256, 0, stream>>>(bufA, rowptr, csrsrc, dinv,
                                                          Wf + WF_B2, bufB, compact);

    // edge MLP via per-node projections
    k_gemm_pair<<<(N_NODES + 255) / 256, 256, 0, stream>>>(bufB, Wf + WF_L1W, bufA, flag, compact);
    k_edge<<<(N_EDGES + 255) / 256, 256, 0, stream>>>(ei, flag, bufA, bufB, Wf, d_out, compact);
}

// Round 5
// 649.243 us; speedup vs baseline: 1.8875x; 1.2767x over previous
//
#include <hip/hip_runtime.h>
#include <hip/hip_bf16.h>

#define N_NODES 100000
#define N_EDGES 1600000
#define F_IN 128
#define HID 64
#define SCAN_NB 98  // ceil(100000/1024)

typedef __attribute__((ext_vector_type(8))) short short8;

__device__ __forceinline__ float bfbits2f(unsigned short u) {
    union { unsigned int i; float f; } v;
    v.i = ((unsigned int)u) << 16;
    return v.f;
}
__device__ __forceinline__ unsigned short f2bfbits(float f) {
    union { float f; unsigned int i; } v;
    v.f = f;
    unsigned int r = v.i + 0x7FFFu + ((v.i >> 16) & 1u);  // RNE
    return (unsigned short)(r >> 16);
}
__device__ __forceinline__ unsigned int pack2bf(float a, float b) {
    return ((unsigned int)f2bfbits(b) << 16) | (unsigned int)f2bfbits(a);
}
__device__ __forceinline__ float lo_bf(unsigned int w) { return bfbits2f((unsigned short)(w & 0xFFFF)); }
__device__ __forceinline__ float hi_bf(unsigned int w) { return bfbits2f((unsigned short)(w >> 16)); }

// ---- runtime flags: flag[0] = edge_index is int64; flag[1] = model dtype is bf16 ----
__global__ void k_detect(const int* __restrict__ ei, const unsigned int* __restrict__ x32,
                         int* __restrict__ flag) {
    __shared__ int s_odd, s_cnt;
    if (threadIdx.x == 0) { s_odd = 0; s_cnt = 0; }
    __syncthreads();
    int t = threadIdx.x;  // blockDim.x == 1024
    if (ei[2 * t + 1] != 0) atomicOr(&s_odd, 1);
    if (t < 256) {
        unsigned int u = x32[t];
        unsigned int e = (u >> 7) & 0xFF;
        if (e >= 0x68 && e <= 0x97) atomicAdd(&s_cnt, 1);
    }
    __syncthreads();
    if (t == 0) {
        flag[0] = (s_odd == 0) ? 1 : 0;
        flag[1] = (s_cnt >= 160) ? 1 : 0;
    }
}

__device__ __forceinline__ int clampN(int v) {
    v = v < 0 ? 0 : v;
    return v > (N_NODES - 1) ? (N_NODES - 1) : v;
}
__device__ __forceinline__ int load_row(const int* __restrict__ ei, int f, int e) {
    return clampN(f ? ei[2 * e] : ei[e]);
}
__device__ __forceinline__ int load_col(const int* __restrict__ ei, int f, int e) {
    return clampN(f ? ei[2 * (N_EDGES + e)] : ei[N_EDGES + e]);
}

// ---- fp32 weight scratch layout (floats) ----
#define WF_W1   0
#define WF_W2   8192
#define WF_L1W  12288
#define WF_B1   20480
#define WF_B2   20544
#define WF_L1B  20608
#define WF_L2W  20672
#define WF_L2B  20800
#define WF_TOT  20802

__global__ void k_prep(const void* W1, const void* W2, const void* L1W,
                       const void* b1, const void* b2, const void* L1b,
                       const void* L2W, const void* L2b,
                       const int* __restrict__ flag, float* __restrict__ Wf) {
    int idx = blockIdx.x * blockDim.x + threadIdx.x;
    if (idx >= WF_TOT) return;
    int bf = flag[1];
    const void* src; int k;
    if      (idx < WF_W2)  { src = W1;  k = idx; }
    else if (idx < WF_L1W) { src = W2;  k = idx - WF_W2; }
    else if (idx < WF_B1)  { src = L1W; k = idx - WF_L1W; }
    else if (idx < WF_B2)  { src = b1;  k = idx - WF_B1; }
    else if (idx < WF_L1B) { src = b2;  k = idx - WF_B2; }
    else if (idx < WF_L2W) { src = L1b; k = idx - WF_L1B; }
    else if (idx < WF_L2B) { src = L2W; k = idx - WF_L2W; }
    else                   { src = L2b; k = idx - WF_L2B; }
    Wf[idx] = bf ? bfbits2f(((const unsigned short*)src)[k]) : ((const float*)src)[k];
}

__global__ void k_deg(const int* __restrict__ ei, const int* __restrict__ flag,
                      int* __restrict__ deg) {
    int e = blockIdx.x * blockDim.x + threadIdx.x;
    if (e >= N_EDGES) return;
    atomicAdd(&deg[load_col(ei, flag[0], e)], 1);
}

__global__ void k_dinv(const int* __restrict__ deg, float* __restrict__ dinv) {
    int i = blockIdx.x * blockDim.x + threadIdx.x;
    if (i < N_NODES) dinv[i] = rsqrtf((float)(deg[i] + 1));
}

// ---- CSR build ----
__global__ void k_scan1(const int* __restrict__ deg, int* __restrict__ rowptr,
                        int* __restrict__ bsum) {
    __shared__ int s[1024];
    int t = threadIdx.x, b = blockIdx.x;
    int i = b * 1024 + t;
    int v = (i < N_NODES) ? deg[i] : 0;
    s[t] = v; __syncthreads();
    for (int off = 1; off < 1024; off <<= 1) {
        int add = (t >= off) ? s[t - off] : 0;
        __syncthreads();
        s[t] += add;
        __syncthreads();
    }
    if (i < N_NODES) rowptr[i] = s[t] - v;
    if (t == 1023) bsum[b] = s[t];
}

__global__ void k_scan2(const int* __restrict__ bsum, int* __restrict__ boff,
                        int* __restrict__ rowptr) {
    __shared__ int s[128];
    int t = threadIdx.x;
    int v = (t < SCAN_NB) ? bsum[t] : 0;
    s[t] = v; __syncthreads();
    for (int off = 1; off < 128; off <<= 1) {
        int add = (t >= off) ? s[t - off] : 0;
        __syncthreads();
        s[t] += add;
        __syncthreads();
    }
    if (t < SCAN_NB) boff[t] = s[t] - v;
    if (t == 0) rowptr[N_NODES] = N_EDGES;
}

__global__ void k_scan3(int* __restrict__ rowptr, const int* __restrict__ boff) {
    int t = threadIdx.x, b = blockIdx.x;
    int i = b * 1024 + t;
    if (i < N_NODES) rowptr[i] += boff[b];
}

__global__ void k_fill(const int* __restrict__ ei, const int* __restrict__ flag,
                       const int* __restrict__ rowptr, int* __restrict__ cursor,
                       int* __restrict__ csr_src, int* __restrict__ csr_col,
                       int* __restrict__ csr_eid) {
    int e = blockIdx.x * blockDim.x + threadIdx.x;
    if (e >= N_EDGES) return;
    int f = flag[0];
    int r = load_row(ei, f, e), c = load_col(ei, f, e);
    int pos = atomicAdd(&cursor[c], 1);
    int slot = rowptr[c] + pos;
    csr_src[slot] = r;
    csr_col[slot] = c;
    csr_eid[slot] = e;
}

// ===== node tables: packed bf16 rows, 32 u32 (=64 ch) per node =====

__device__ __forceinline__ void st_row_bf(unsigned int* tab, int node, const float* acc, float s) {
    unsigned int* op = tab + (size_t)node * 32;
#pragma unroll
    for (int j = 0; j < 64; j += 2) op[j >> 1] = pack2bf(acc[j] * s, acc[j + 1] * s);
}

__device__ __forceinline__ void fma8(const float* xv, const float* __restrict__ Wf,
                                     int k0, float* acc) {
#pragma unroll
    for (int t = 0; t < 8; t++) {
        const float* wr = Wf + (k0 + t) * 64;
#pragma unroll
        for (int j = 0; j < 64; j++) acc[j] = fmaf(xv[t], wr[j], acc[j]);
    }
}

// ---- layer-1 GEMM: x [N,128] (bf16 or fp32) @ Wf[128,64] -> hs (bf16 rows) ----
__global__ void __launch_bounds__(256) k_gemm_in(const void* __restrict__ x,
                                                 const float* __restrict__ Wf,
                                                 const float* __restrict__ dinv,
                                                 unsigned int* __restrict__ hs,
                                                 const int* __restrict__ flag) {
    int i = blockIdx.x * blockDim.x + threadIdx.x;
    if (i >= N_NODES) return;
    int bf = flag[1];
    float acc[64];
#pragma unroll
    for (int j = 0; j < 64; j++) acc[j] = 0.f;
    if (bf) {
        const unsigned short* xp = (const unsigned short*)x + (size_t)i * F_IN;
#pragma unroll 2
        for (int k0 = 0; k0 < F_IN; k0 += 8) {
            short8 raw = *(const short8*)(xp + k0);
            float xv[8];
#pragma unroll
            for (int t = 0; t < 8; t++) xv[t] = bfbits2f((unsigned short)raw[t]);
            fma8(xv, Wf, k0, acc);
        }
    } else {
        const float* xp = (const float*)x + (size_t)i * F_IN;
#pragma unroll 2
        for (int k0 = 0; k0 < F_IN; k0 += 8) {
            float4 a = *(const float4*)(xp + k0);
            float4 b = *(const float4*)(xp + k0 + 4);
            float xv[8] = {a.x, a.y, a.z, a.w, b.x, b.y, b.z, b.w};
            fma8(xv, Wf, k0, acc);
        }
    }
    st_row_bf(hs, i, acc, dinv[i]);
}

// ---- layer-2 GEMM: h (bf16 rows) @ Wf[64,64] -> hs (bf16 rows) ----
__global__ void __launch_bounds__(256) k_gemm_h(const unsigned int* __restrict__ h,
                                                const float* __restrict__ Wf,
                                                const float* __restrict__ dinv,
                                                unsigned int* __restrict__ hs) {
    int i = blockIdx.x * blockDim.x + threadIdx.x;
    if (i >= N_NODES) return;
    float acc[64];
#pragma unroll
    for (int j = 0; j < 64; j++) acc[j] = 0.f;
    const unsigned short* hp = (const unsigned short*)(h + (size_t)i * 32);
#pragma unroll 2
    for (int k0 = 0; k0 < 64; k0 += 8) {
        short8 raw = *(const short8*)(hp + k0);
        float xv[8];
#pragma unroll
        for (int t = 0; t < 8; t++) xv[t] = bfbits2f((unsigned short)raw[t]);
        fma8(xv, Wf, k0, acc);
    }
    st_row_bf(hs, i, acc, dinv[i]);
}

// ---- fused aggregate: wave = 2 nodes; 32 lanes/node; lane w handles ch 2w,2w+1 ----
// h[i] = relu( dinv[i] * (hs[i] + sum_{r in in(i)} hs[r]) + bias )
__global__ void __launch_bounds__(256) k_agg(const unsigned int* __restrict__ hs,
                                             const int* __restrict__ rowptr,
                                             const int* __restrict__ csr_src,
                                             const float* __restrict__ dinv,
                                             const float* __restrict__ bias,
                                             unsigned int* __restrict__ h) {
    int waves_per_blk = blockDim.x >> 6;
    int wid = blockIdx.x * waves_per_blk + (threadIdx.x >> 6);
    int lane = threadIdx.x & 63;
    int half = lane >> 5;
    int w = lane & 31;
    int node = wid * 2 + half;
    if (node >= N_NODES) return;
    unsigned int sw = hs[(size_t)node * 32 + w];
    float a0 = lo_bf(sw), a1 = hi_bf(sw);
    int k = rowptr[node], k1 = rowptr[node + 1];
    for (; k + 1 < k1; k += 2) {
        int s0 = csr_src[k], s1 = csr_src[k + 1];
        unsigned int w0 = hs[(size_t)s0 * 32 + w];
        unsigned int w1 = hs[(size_t)s1 * 32 + w];
        a0 += lo_bf(w0) + lo_bf(w1);
        a1 += hi_bf(w0) + hi_bf(w1);
    }
    if (k < k1) {
        unsigned int w0 = hs[(size_t)csr_src[k] * 32 + w];
        a0 += lo_bf(w0);
        a1 += hi_bf(w0);
    }
    float di = dinv[node];
    float v0 = fmaxf(fmaf(a0, di, bias[2 * w]), 0.f);
    float v1 = fmaxf(fmaf(a1, di, bias[2 * w + 1]), 0.f);
    h[(size_t)node * 32 + w] = pack2bf(v0, v1);
}

// ---- per-node projections: P1 = h@L1W[:64] -> hs region; P2 = h@L1W[64:] -> h row in place ----
__global__ void __launch_bounds__(256) k_gemm_pair(unsigned int* __restrict__ h,
                                                   const float* __restrict__ Wf,  // [128][64]
                                                   unsigned int* __restrict__ P1) {
    int i = blockIdx.x * blockDim.x + threadIdx.x;
    if (i >= N_NODES) return;
    float a0[64], a1[64];
#pragma unroll
    for (int j = 0; j < 64; j++) { a0[j] = 0.f; a1[j] = 0.f; }
    const unsigned short* hp = (const unsigned short*)(h + (size_t)i * 32);
#pragma unroll 1
    for (int k0 = 0; k0 < 64; k0 += 8) {
        short8 raw = *(const short8*)(hp + k0);
        float xv[8];
#pragma unroll
        for (int t = 0; t < 8; t++) xv[t] = bfbits2f((unsigned short)raw[t]);
#pragma unroll
        for (int t = 0; t < 8; t++) {
            const float* wrA = Wf + (k0 + t) * 64;
            const float* wrB = Wf + (64 + k0 + t) * 64;
#pragma unroll
            for (int j = 0; j < 64; j++) {
                a0[j] = fmaf(xv[t], wrA[j], a0[j]);
                a1[j] = fmaf(xv[t], wrB[j], a1[j]);
            }
        }
    }
    unsigned int* p1 = P1 + (size_t)i * 32;
    unsigned int* p2 = h + (size_t)i * 32;  // own row fully consumed above
#pragma unroll
    for (int j = 0; j < 64; j += 2) {
        p1[j >> 1] = pack2bf(a0[j], a0[j + 1]);
        p2[j >> 1] = pack2bf(a1[j], a1[j + 1]);
    }
}

// ---- edge MLP in CSR order: thread = CSR slot; c nearly-sequential -> P2 cached ----
__global__ void k_edge(const int* __restrict__ csr_src, const int* __restrict__ csr_col,
                       const int* __restrict__ csr_eid,
                       const unsigned int* __restrict__ P1, const unsigned int* __restrict__ P2,
                       const float* __restrict__ Wf, const int* __restrict__ flag,
                       void* __restrict__ out) {
    int s = blockIdx.x * blockDim.x + threadIdx.x;
    if (s >= N_EDGES) return;
    int r = csr_src[s], c = csr_col[s], eid = csr_eid[s];
    const float* l1b = Wf + WF_L1B;
    const float* l2w = Wf + WF_L2W;
    const float* l2b = Wf + WF_L2B;
    const uint4* p1 = (const uint4*)(P1 + (size_t)r * 32);
    const uint4* p2 = (const uint4*)(P2 + (size_t)c * 32);
    float s0 = 0.f, s1 = 0.f;
#pragma unroll
    for (int q = 0; q < 8; q++) {
        uint4 ua = p1[q];
        uint4 ub = p2[q];
        unsigned int wa[4] = {ua.x, ua.y, ua.z, ua.w};
        unsigned int wb[4] = {ub.x, ub.y, ub.z, ub.w};
#pragma unroll
        for (int t = 0; t < 4; t++) {
            int j = q * 8 + t * 2;
            float z;
            z = fmaxf(lo_bf(wa[t]) + lo_bf(wb[t]) + l1b[j + 0], 0.f);
            s0 = fmaf(z, l2w[(j + 0) * 2], s0); s1 = fmaf(z, l2w[(j + 0) * 2 + 1], s1);
            z = fmaxf(hi_bf(wa[t]) + hi_bf(wb[t]) + l1b[j + 1], 0.f);
            s0 = fmaf(z, l2w[(j + 1) * 2], s0); s1 = fmaf(z, l2w[(j + 1) * 2 + 1], s1);
        }
    }
    float z0 = s0 + l2b[0];
    float z1 = s1 + l2b[1];
    float m = fmaxf(z0, z1);
    float lse = m + __logf(__expf(z0 - m) + __expf(z1 - m));
    if (flag[1]) {
        ((unsigned int*)out)[eid] = pack2bf(z0 - lse, z1 - lse);
    } else {
        float2 v; v.x = z0 - lse; v.y = z1 - lse;
        ((float2*)out)[eid] = v;
    }
}

extern "C" void kernel_launch(void* const* d_in, const int* in_sizes, int n_in,
                              void* d_out, int out_size, void* d_ws, size_t ws_size,
                              hipStream_t stream) {
    const void* x   = d_in[0];
    const int*  ei  = (const int*)d_in[1];

    char* ws = (char*)d_ws;
    constexpr size_t KB = 1024;
    constexpr size_t MiB = 1024 * 1024;

    // total peak use ~47.97 MB (under the 48.7 MB proven-safe bound from round 4)
    int*   deg    = (int*)(ws);                        // 400 KB (reused as cursor)
    float* dinv   = (float*)(ws + 512 * KB);           // 400 KB
    int*   flag   = (int*)(ws + 960 * KB);             // 8 B
    float* Wf     = (float*)(ws + 1 * MiB);            // 83.2 KB
    int*   bsum   = (int*)(ws + 1 * MiB + 96 * KB);    // 392 B
    int*   boff   = (int*)(ws + 1 * MiB + 100 * KB);   // 392 B
    int*   rowptr = (int*)(ws + 1 * MiB + 128 * KB);   // 400 KB + 4
    int*   csrsrc = (int*)(ws + 2 * MiB);              // 6.4 MB
    int*   csreid = (int*)(ws + 2 * MiB + 6400 * KB);  // 6.4 MB
    int*   csrcol = (int*)(ws + 2 * MiB + 12800 * KB); // 6.4 MB
    unsigned int* hs = (unsigned int*)(ws + 2 * MiB + 19200 * KB);  // 12.8 MB (later P1)
    unsigned int* h  = (unsigned int*)(ws + 2 * MiB + 32000 * KB);  // 12.8 MB (later P2)

    hipMemsetAsync(deg, 0, N_NODES * sizeof(int), stream);

    k_detect<<<1, 1024, 0, stream>>>(ei, (const unsigned int*)x, flag);
    k_prep<<<(WF_TOT + 255) / 256, 256, 0, stream>>>(d_in[2], d_in[4], d_in[6], d_in[3],
                                                     d_in[5], d_in[7], d_in[8], d_in[9],
                                                     flag, Wf);
    k_deg<<<(N_EDGES + 255) / 256, 256, 0, stream>>>(ei, flag, deg);
    k_dinv<<<(N_NODES + 255) / 256, 256, 0, stream>>>(deg, dinv);

    // CSR build (by target col), keeping original edge id for the output scatter
    k_scan1<<<SCAN_NB, 1024, 0, stream>>>(deg, rowptr, bsum);
    k_scan2<<<1, 128, 0, stream>>>(bsum, boff, rowptr);
    k_scan3<<<SCAN_NB, 1024, 0, stream>>>(rowptr, boff);
    hipMemsetAsync(deg, 0, N_NODES * sizeof(int), stream);  // deg -> cursor
    k_fill<<<(N_EDGES + 255) / 256, 256, 0, stream>>>(ei, flag, rowptr, deg,
                                                      csrsrc, csrcol, csreid);

    // layer 1
    k_gemm_in<<<(N_NODES + 255) / 256, 256, 0, stream>>>(x, Wf + WF_W1, dinv, hs, flag);
    k_agg<<<(N_NODES / 2 + 3) / 4, 256, 0, stream>>>(hs, rowptr, csrsrc, dinv, Wf + WF_B1, h);

    // layer 2
    k_gemm_h<<<(N_NODES + 255) / 256, 256, 0, stream>>>(h, Wf + WF_W2, dinv, hs);
    k_agg<<<(N_NODES / 2 + 3) / 4, 256, 0, stream>>>(hs, rowptr, csrsrc, dinv, Wf + WF_B2, h);

    // edge MLP: P1 -> hs region, P2 -> h rows in place; then CSR-ordered edge pass
    k_gemm_pair<<<(N_NODES + 255) / 256, 256, 0, stream>>>(h, Wf + WF_L1W, hs);
    k_edge<<<(N_EDGES + 255) / 256, 256, 0, stream>>>(csrsrc, csrcol, csreid,
                                                      hs, h, Wf, flag, d_out);
}